// Round 21
// baseline (225.886 us; speedup 1.0000x reference)
//
#include <hip/hip_runtime.h>

#define BB 8
#define NN 1024
#define CC 64
#define TT 12
#define OO 64

typedef unsigned short u16;
typedef __attribute__((ext_vector_type(8))) short s16x8;
typedef __attribute__((ext_vector_type(4))) float f32x4;
typedef __attribute__((ext_vector_type(4))) unsigned int u32x4;
typedef __attribute__((ext_vector_type(2))) unsigned int u32x2;

__device__ __forceinline__ u16 f2bu(float f){
  union { float f; unsigned u; } v; v.f = f;
  unsigned r = v.u + 0x7FFFu + ((v.u >> 16) & 1u);
  return (u16)(r >> 16);
}
__device__ __forceinline__ float b2f(u16 h){
  union { unsigned u; float f; } v; v.u = ((unsigned)h) << 16; return v.f;
}
// q = relu(tanh(d)) = max(1 - 2/(exp(2d)+1), 0)
__device__ __forceinline__ float relu_tanh(float d){
  float e = __expf(2.0f * d);
  return fmaxf(1.0f - 2.0f * __builtin_amdgcn_rcpf(e + 1.0f), 0.0f);
}
// signed tanh via the same 2-transcendental form
__device__ __forceinline__ float tanh_fast(float d){
  float e = __expf(2.0f * d);
  return 1.0f - 2.0f * __builtin_amdgcn_rcpf(e + 1.0f);
}
__device__ __forceinline__ float tanh_sgn(float x){
  float ax = fabsf(x);
  float e = __expf(2.0f * ax);
  float t = 1.0f - 2.0f * __builtin_amdgcn_rcpf(e + 1.0f);
  return x < 0.0f ? -t : t;
}

#define MFMA16(a,b,c) __builtin_amdgcn_mfma_f32_16x16x32_bf16((a),(b),(c),0,0,0)

// frag load from padded-72 row-major LDS tile (row stride 144B = 9x16B, aligned)
__device__ __forceinline__ s16x8 ld72(const u16* s, int row0, int ko, int lane){
  return *(const s16x8*)(s + (row0 + (lane & 15)) * 72 + ko + ((lane >> 4) << 3));
}

// ---------------- K0: x [B,N,C,T] f32 -> xt [T,B,N,C] bf16 ----------------
__global__ __launch_bounds__(256) void k0_transpose(const float* __restrict__ x,
                                                    u16* __restrict__ xt){
  const int n = blockIdx.x, b = blockIdx.y;
  __shared__ float s[CC*TT];
  const float* src = x + (size_t)(b*NN + n)*CC*TT;
  for (int k = threadIdx.x; k < CC*TT; k += 256) s[k] = src[k];
  __syncthreads();
  for (int k = threadIdx.x; k < CC*TT; k += 256){
    const int t = k >> 6, c = k & 63;
    xt[(((size_t)t*BB + b)*NN + n)*CC + c] = f2bu(s[c*TT + t]);
  }
}

// ------ kprep: adj f32 -> bf16 AND rowsum init (merged launches) ------
__global__ __launch_bounds__(256) void kprep(const float* __restrict__ adj,
                                             u16* __restrict__ adjb,
                                             float* __restrict__ rs){
  const size_t i = ((size_t)blockIdx.x*256 + threadIdx.x)*4;
  if (i < (size_t)NN*NN){
    const float4 v = *(const float4*)(adj + i);
    u16 o0=f2bu(v.x), o1=f2bu(v.y), o2=f2bu(v.z), o3=f2bu(v.w);
    adjb[i]=o0; adjb[i+1]=o1; adjb[i+2]=o2; adjb[i+3]=o3;
  }
  const size_t j = (size_t)blockIdx.x*256 + threadIdx.x;
  if (j < (size_t)TT*BB*NN) rs[j] = 1.0f;   // +I contribution to degree
}

// ---- K1: base = xt@Wd + bd; DE1/2 = tanh(base*E1/2), direct stores ----
__global__ __launch_bounds__(256) void k1_de(const u16* __restrict__ xt,
    const float* __restrict__ Wd, const float* __restrict__ bd,
    const float* __restrict__ E1, const float* __restrict__ E2,
    u16* __restrict__ DE1g, u16* __restrict__ DE2g){
  __shared__ __align__(16) u16 sWd[64*72];   // W^T [o][c]
  const int tid = threadIdx.x, lane = tid & 63, wid = tid >> 6;
  const int l15 = lane & 15, lr4 = lane >> 4;
  const int it = blockIdx.x, b = blockIdx.y, t = blockIdx.z;
  const int n0 = it * 64;
  for (int k = tid; k < 4096; k += 256){
    const int o = k & 63, c = k >> 6;
    sWd[o*72 + c] = f2bu(Wd[(size_t)t*4096 + c*64 + o]);
  }
  __syncthreads();
  const size_t tb = (size_t)t*BB + b;
  const u16* gx = xt + (tb*NN + n0)*CC;
  const int wrow = wid * 16;
  const f32x4 fz = {0.f,0.f,0.f,0.f};
  f32x4 acc[4] = {fz, fz, fz, fz};
  #pragma unroll
  for (int ks = 0; ks < 2; ++ks){
    const int ko = ks*32;
    const s16x8 a = *(const s16x8*)(gx + (wrow + l15)*CC + ko + (lr4 << 3));
    #pragma unroll
    for (int v = 0; v < 4; ++v)
      acc[v] = MFMA16(a, ld72(sWd, v*16, ko, lane), acc[v]);
  }
  #pragma unroll
  for (int v = 0; v < 4; ++v){
    const int o = v*16 + l15;
    const float bdv = bd[t*OO + o];
    #pragma unroll
    for (int e = 0; e < 4; ++e){
      const int n = n0 + wrow + (lr4 << 2) + e;
      const float base = acc[v][e] + bdv;
      const size_t eo = ((size_t)t*NN + n)*OO + o;
      const size_t so = (tb*NN + n)*OO + o;
      DE1g[so] = f2bu(tanh_sgn(base * E1[eo]));
      DE2g[so] = f2bu(tanh_sgn(base * E2[eo]));
    }
  }
}

// ---- K2a: PASS 1 — rowsum via UPPER-TRIANGLE only. Strip pair (p, 15-p),
//      j-tiles DOUBLE-BUFFERED in the dead i-side buffers: 1 barrier/iter. ----
__global__ __launch_bounds__(256) void k2a(const u16* __restrict__ DE1g,
    const u16* __restrict__ DE2g, float* __restrict__ rowsum){
  __shared__ __align__(16) u16 sb0[64*72], sb1[64*72];     // buf pair 0
  __shared__ __align__(16) u16 sb2[64*72], sb3[64*72];     // buf pair 1
  const int tid = threadIdx.x, lane = tid & 63, wid = tid >> 6;
  const int l15 = lane & 15, lr4 = lane >> 4;
  const int nwg = 8*BB*TT;                                 // 768
  const int logical = ((int)blockIdx.x & 7)*(nwg >> 3) + ((int)blockIdx.x >> 3);
  const int p = logical & 7;
  const size_t tb = (size_t)(logical >> 3);                // t*BB + b
  const int tiA = p, tiB = 15 - p;
  const u16* g1 = DE1g + tb*NN*OO;
  const u16* g2 = DE2g + tb*NN*OO;
  for (int k = tid; k < 512; k += 256){
    const int r = k >> 3, c = (k & 7) << 3;
    *(s16x8*)(sb0 + r*72 + c) = *(const s16x8*)(g1 + (size_t)(tiA*64 + r)*OO + c);
    s16x8 vA = *(const s16x8*)(g2 + (size_t)(tiA*64 + r)*OO + c);
    u32x4 wA = *(u32x4*)&vA; wA ^= 0x80008000u;            // negate 8 bf16
    *(u32x4*)(sb1 + r*72 + c) = wA;
    *(s16x8*)(sb2 + r*72 + c) = *(const s16x8*)(g1 + (size_t)(tiB*64 + r)*OO + c);
    s16x8 vB = *(const s16x8*)(g2 + (size_t)(tiB*64 + r)*OO + c);
    u32x4 wB = *(u32x4*)&vB; wB ^= 0x80008000u;
    *(u32x4*)(sb3 + r*72 + c) = wB;
  }
  __syncthreads();
  const int wrow = wid * 16;
  s16x8 a1A[2], na2A[2], a1B[2], na2B[2];
  #pragma unroll
  for (int ks = 0; ks < 2; ++ks){
    a1A[ks]  = ld72(sb0, wrow, ks*32, lane);
    na2A[ks] = ld72(sb1, wrow, ks*32, lane);
    a1B[ks]  = ld72(sb2, wrow, ks*32, lane);
    na2B[ks] = ld72(sb3, wrow, ks*32, lane);
  }
  const int srow = tid >> 2, sc0 = (tid & 3) << 4;
  s16x8 pB1a,pB1b, pB2a,pB2b;
#define LOADT(TJ) do { \
    pB1a = *(const s16x8*)(g2 + (size_t)((TJ)*64 + srow)*OO + sc0); \
    pB1b = *(const s16x8*)(g2 + (size_t)((TJ)*64 + srow)*OO + sc0 + 8); \
    pB2a = *(const s16x8*)(g1 + (size_t)((TJ)*64 + srow)*OO + sc0); \
    pB2b = *(const s16x8*)(g1 + (size_t)((TJ)*64 + srow)*OO + sc0 + 8); \
  } while (0)
  LOADT(p);
  float rpA[4] = {0.f,0.f,0.f,0.f}, rpB[4] = {0.f,0.f,0.f,0.f};
  const f32x4 fz = {0.f,0.f,0.f,0.f};
  float* rsg = rowsum + tb*NN;
  __syncthreads();                      // all waves hold a-frags before overwrite
  for (int tj = p; tj < 16; ++tj){
    u16* sJ1 = ((tj - p) & 1) ? sb2 : sb0;
    u16* sJ2 = ((tj - p) & 1) ? sb3 : sb1;
    *(s16x8*)(sJ1 + srow*72 + sc0)     = pB1a;
    *(s16x8*)(sJ1 + srow*72 + sc0 + 8) = pB1b;
    *(s16x8*)(sJ2 + srow*72 + sc0)     = pB2a;
    *(s16x8*)(sJ2 + srow*72 + sc0 + 8) = pB2b;
    __syncthreads();                    // single barrier: dbuf covers the tail
    if (tj < 15) LOADT(tj + 1);         // T14: issue early, lands next iter
    s16x8 b1[4], b2[4], b1h[4], b2h[4];
    #pragma unroll
    for (int v = 0; v < 4; ++v){
      b1[v]  = ld72(sJ1, v*16, 0,  lane);
      b2[v]  = ld72(sJ2, v*16, 0,  lane);
      b1h[v] = ld72(sJ1, v*16, 32, lane);
      b2h[v] = ld72(sJ2, v*16, 32, lane);
    }
    {   // strip A
      f32x4 z[4];
      #pragma unroll
      for (int v = 0; v < 4; ++v){
        z[v] = MFMA16(a1A[0],  b1[v],  fz);
        z[v] = MFMA16(na2A[0], b2[v],  z[v]);
        z[v] = MFMA16(a1A[1],  b1h[v], z[v]);
        z[v] = MFMA16(na2A[1], b2h[v], z[v]);
      }
      float colp[4] = {0.f,0.f,0.f,0.f};
      #pragma unroll
      for (int v = 0; v < 4; ++v)
        #pragma unroll
        for (int e = 0; e < 4; ++e){
          const float th = tanh_fast(z[v][e]);
          rpA[e]  += fmaxf(th, 0.f);
          colp[v] += fmaxf(-th, 0.f);
        }
      if (tj > tiA){
        #pragma unroll
        for (int v = 0; v < 4; ++v){
          float c = colp[v];
          c += __shfl_xor(c, 16); c += __shfl_xor(c, 32);
          if (lane < 16) atomicAdd(&rsg[tj*64 + v*16 + lane], c);
        }
      }
    }
    if (tj >= tiB){   // strip B
      f32x4 z[4];
      #pragma unroll
      for (int v = 0; v < 4; ++v){
        z[v] = MFMA16(a1B[0],  b1[v],  fz);
        z[v] = MFMA16(na2B[0], b2[v],  z[v]);
        z[v] = MFMA16(a1B[1],  b1h[v], z[v]);
        z[v] = MFMA16(na2B[1], b2h[v], z[v]);
      }
      float colp[4] = {0.f,0.f,0.f,0.f};
      #pragma unroll
      for (int v = 0; v < 4; ++v)
        #pragma unroll
        for (int e = 0; e < 4; ++e){
          const float th = tanh_fast(z[v][e]);
          rpB[e]  += fmaxf(th, 0.f);
          colp[v] += fmaxf(-th, 0.f);
        }
      if (tj > tiB){
        #pragma unroll
        for (int v = 0; v < 4; ++v){
          float c = colp[v];
          c += __shfl_xor(c, 16); c += __shfl_xor(c, 32);
          if (lane < 16) atomicAdd(&rsg[tj*64 + v*16 + lane], c);
        }
      }
    }
  }
#undef LOADT
  #pragma unroll
  for (int e = 0; e < 4; ++e){
    float r = rpA[e];
    r += __shfl_xor(r, 1); r += __shfl_xor(r, 2);
    r += __shfl_xor(r, 4); r += __shfl_xor(r, 8);
    if (l15 == 0) atomicAdd(&rsg[tiA*64 + wrow + (lr4 << 2) + e], r);
  }
  #pragma unroll
  for (int e = 0; e < 4; ++e){
    float r = rpB[e];
    r += __shfl_xor(r, 1); r += __shfl_xor(r, 2);
    r += __shfl_xor(r, 4); r += __shfl_xor(r, 8);
    if (l15 == 0) atomicAdd(&rsg[tiB*64 + wrow + (lr4 << 2) + e], r);
  }
}

// ---- K3b (after k2a): xdv' = rsqrt(rowsum)*0.475*x@Wd ; xsw' = 0.475*x@Ws
//      ([o][n]); x0w = 0.05*x@W0 + all biases ([n][o]) ----
__global__ __launch_bounds__(256) void k3b(const u16* __restrict__ xt,
    const float* __restrict__ Wd, const float* __restrict__ Ws,
    const float* __restrict__ W0, const float* __restrict__ bd,
    const float* __restrict__ bs, const float* __restrict__ b0,
    const float* __restrict__ rowsum, u16* __restrict__ xdvT,
    u16* __restrict__ xswT, u16* __restrict__ x0w){
  __shared__ __align__(16) u16 sW[64*72];
  const int tid = threadIdx.x, lane = tid & 63, wid = tid >> 6;
  const int l15 = lane & 15, lr4 = lane >> 4;
  const int it = blockIdx.x, b = blockIdx.y, t = blockIdx.z;
  const size_t tb = (size_t)t*BB + b;
  const int n0 = it * 128, wrow = wid * 32;
  const float* dvb = rowsum + tb*NN + n0;
  float dis[2][4];
  #pragma unroll
  for (int u = 0; u < 2; ++u)
    #pragma unroll
    for (int e = 0; e < 4; ++e)
      dis[u][e] = rsqrtf(dvb[wrow + u*16 + (lr4 << 2) + e]);
  float badd[4];
  #pragma unroll
  for (int v = 0; v < 4; ++v){
    const int o = v*16 + l15;
    badd[v] = 0.475f*(bd[t*OO + o] + bs[t*OO + o]) + 0.05f*b0[o];
  }
  const u16* gx = xt + (tb*NN + n0)*CC;
  const f32x4 fz = {0.f,0.f,0.f,0.f};
  for (int pass = 0; pass < 3; ++pass){
    __syncthreads();
    {
      const float* Wsrc = (pass == 0) ? (Wd + (size_t)t*4096)
                        : (pass == 1) ? (Ws + (size_t)t*4096) : W0;
      const float scale = (pass == 2) ? 0.05f : 0.475f;
      for (int k = tid; k < 4096; k += 256){
        const int o = k & 63, c = k >> 6;
        sW[o*72 + c] = f2bu(scale * Wsrc[c*64 + o]);
      }
    }
    __syncthreads();
    f32x4 acc[2][4];
    #pragma unroll
    for (int u = 0; u < 2; ++u)
      #pragma unroll
      for (int v = 0; v < 4; ++v) acc[u][v] = fz;
    #pragma unroll
    for (int ks = 0; ks < 2; ++ks){
      const int ko = ks*32;
      s16x8 bw[4];
      #pragma unroll
      for (int v = 0; v < 4; ++v) bw[v] = ld72(sW, v*16, ko, lane);
      #pragma unroll
      for (int u = 0; u < 2; ++u){
        const s16x8 a = *(const s16x8*)(gx + (wrow + u*16 + l15)*CC + ko + (lr4 << 3));
        #pragma unroll
        for (int v = 0; v < 4; ++v) acc[u][v] = MFMA16(a, bw[v], acc[u][v]);
      }
    }
    #pragma unroll
    for (int u = 0; u < 2; ++u)
      #pragma unroll
      for (int v = 0; v < 4; ++v){
        const int o = v*16 + l15;
        #pragma unroll
        for (int e = 0; e < 4; ++e){
          const int nl = wrow + u*16 + (lr4 << 2) + e;
          float val = acc[u][v][e];
          if (pass == 0)      xdvT[(tb*OO + o)*NN + n0 + nl] = f2bu(val * dis[u][e]);
          else if (pass == 1) xswT[(tb*OO + o)*NN + n0 + nl] = f2bu(val);
          else                x0w[(tb*NN + n0 + nl)*OO + o]  = f2bu(val + badd[v]);
        }
      }
  }
}

// ---- K4s: outSta = adj@xsw'  (bf16, [n][o]) — ti-major XCD swizzle. ----
__global__ __launch_bounds__(256) void k4s(const u16* __restrict__ adjb,
    const u16* __restrict__ xswT, u16* __restrict__ outSta){
  __shared__ __align__(16) u16 sJ[64*72], sS[64*72];   // 18.4KB
  const int tid = threadIdx.x, lane = tid & 63, wid = tid >> 6;
  const int l15 = lane & 15, lr4 = lane >> 4;
  const int nwg = 16*BB*TT;                            // 1536
  const int logical = ((int)blockIdx.x & 7)*(nwg >> 3) + ((int)blockIdx.x >> 3);
  const int ti = logical / (BB*TT);                    // ti-major: adj reuse
  const size_t tb = (size_t)(logical % (BB*TT));
  const u16* xs = xswT + tb*OO*NN;
  const int i0 = ti * 64, wrow = wid * 16;
  const int srow = tid >> 2, sc0 = (tid & 3) << 4;
  s16x8 pJa, pJb, pSa, pSb;
#define LOADS(TJ) do { \
    pJa = *(const s16x8*)(adjb + (size_t)(i0 + srow)*NN + (TJ)*64 + sc0); \
    pJb = *(const s16x8*)(adjb + (size_t)(i0 + srow)*NN + (TJ)*64 + sc0 + 8); \
    pSa = *(const s16x8*)(xs   + (size_t)srow*NN + (TJ)*64 + sc0); \
    pSb = *(const s16x8*)(xs   + (size_t)srow*NN + (TJ)*64 + sc0 + 8); \
  } while (0)
  LOADS(0);
  const f32x4 fz = {0.f,0.f,0.f,0.f};
  f32x4 as_[4] = {fz,fz,fz,fz};
  for (int tj = 0; tj < 16; ++tj){
    *(s16x8*)(sJ + srow*72 + sc0)     = pJa;
    *(s16x8*)(sJ + srow*72 + sc0 + 8) = pJb;
    *(s16x8*)(sS + srow*72 + sc0)     = pSa;
    *(s16x8*)(sS + srow*72 + sc0 + 8) = pSb;
    __syncthreads();
    if (tj < 15) LOADS(tj + 1);        // T14: lands during compute
    const s16x8 aJ0 = ld72(sJ, wrow, 0,  lane);
    const s16x8 aJ1 = ld72(sJ, wrow, 32, lane);
    #pragma unroll
    for (int v = 0; v < 4; ++v){
      as_[v] = MFMA16(aJ0, ld72(sS, v*16, 0,  lane), as_[v]);
      as_[v] = MFMA16(aJ1, ld72(sS, v*16, 32, lane), as_[v]);
    }
    __syncthreads();                   // frag reads done before next ds_write
  }
#undef LOADS
  #pragma unroll
  for (int v = 0; v < 4; ++v){
    const int o = v*16 + l15;
    #pragma unroll
    for (int e = 0; e < 4; ++e){
      const int n = i0 + wrow + (lr4 << 2) + e;
      outSta[(tb*NN + n)*OO + o] = f2bu(as_[v][e]);
    }
  }
}

// ---- K2bf: PASS 2 — swapped MFMA (y = z^T); A-frags in registers (cvt_pk);
//      ALL buffers double-buffered -> SINGLE barrier per iteration. ----
__global__ __launch_bounds__(256) void k2bf(const u16* __restrict__ DE1g,
    const u16* __restrict__ DE2g, const u16* __restrict__ xdvT,
    const float* __restrict__ rowsum, float* __restrict__ outT){
  __shared__ __align__(16) u16 sB1[2][64*72], sB2[2][64*72], sXD[2][64*72]; // 55.3KB
  const int tid = threadIdx.x, lane = tid & 63, wid = tid >> 6;
  const int l15 = lane & 15, lr4 = lane >> 4;
  const int nwg = 16*BB*TT;                                // 1536
  const int logical = ((int)blockIdx.x & 7)*(nwg >> 3) + ((int)blockIdx.x >> 3);
  const int ti = logical & 15;
  const size_t tb = (size_t)(logical >> 4);                // t*BB + b
  const u16* g1 = DE1g + tb*NN*OO;
  const u16* g2 = DE2g + tb*NN*OO;
  const u16* xd = xdvT + tb*OO*NN;
  const float* dv = rowsum + tb*NN;
  const int i0 = ti * 64;
  // stage i-side into sB1[0]/sB2[0] (dead after a-frag extraction)
  for (int k = tid; k < 512; k += 256){
    const int r = k >> 3, c = (k & 7) << 3;
    *(s16x8*)(sB1[0] + r*72 + c) = *(const s16x8*)(g1 + (size_t)(i0 + r)*OO + c);
    s16x8 v = *(const s16x8*)(g2 + (size_t)(i0 + r)*OO + c);
    u32x4 w = *(u32x4*)&v; w ^= 0x80008000u;
    *(u32x4*)(sB2[0] + r*72 + c) = w;
  }
  __syncthreads();
  const int wrow = wid * 16;
  s16x8 a1[2], na2[2];
  #pragma unroll
  for (int ks = 0; ks < 2; ++ks){
    a1[ks]  = ld72(sB1[0], wrow, ks*32, lane);
    na2[ks] = ld72(sB2[0], wrow, ks*32, lane);
  }
  const int srow = tid >> 2, sc0 = (tid & 3) << 4;
  // sigma^-1 k-positions for the 4 j-groups this thread stages (8B each):
  // g = sc0/4 + q;  kappa = (g&3)*8 + ((g>>2)&1)*4 + (g>>3)*32
  const int g0 = sc0 >> 2;
  int kap[4];
  #pragma unroll
  for (int q = 0; q < 4; ++q){
    const int g = g0 + q;
    kap[q] = ((g & 3) << 3) + (((g >> 2) & 1) << 2) + ((g >> 3) << 5);
  }
  s16x8 pB1a,pB1b, pB2a,pB2b, pXDa,pXDb;
#define LOADT(TJ) do { \
    pB1a = *(const s16x8*)(g2 + (size_t)((TJ)*64 + srow)*OO + sc0); \
    pB1b = *(const s16x8*)(g2 + (size_t)((TJ)*64 + srow)*OO + sc0 + 8); \
    pB2a = *(const s16x8*)(g1 + (size_t)((TJ)*64 + srow)*OO + sc0); \
    pB2b = *(const s16x8*)(g1 + (size_t)((TJ)*64 + srow)*OO + sc0 + 8); \
    pXDa = *(const s16x8*)(xd + (size_t)srow*NN + (TJ)*64 + sc0); \
    pXDb = *(const s16x8*)(xd + (size_t)srow*NN + (TJ)*64 + sc0 + 8); \
  } while (0)
  LOADT(0);
  const f32x4 fz = {0.f,0.f,0.f,0.f};
  f32x4 ad[4] = {fz,fz,fz,fz};
  __syncthreads();                      // all waves read a-frags before overwrite
  for (int tj = 0; tj < 16; ++tj){
    const int cur = tj & 1;
    *(s16x8*)(sB1[cur] + srow*72 + sc0)     = pB1a;
    *(s16x8*)(sB1[cur] + srow*72 + sc0 + 8) = pB1b;
    *(s16x8*)(sB2[cur] + srow*72 + sc0)     = pB2a;
    *(s16x8*)(sB2[cur] + srow*72 + sc0 + 8) = pB2b;
    {   // xdv staged into sigma-permuted k-columns (4x b64)
      const u32x4 xa = *(const u32x4*)&pXDa;
      const u32x4 xb = *(const u32x4*)&pXDb;
      u32x2 h;
      h[0] = xa[0]; h[1] = xa[1];
      *(u32x2*)(sXD[cur] + srow*72 + kap[0]) = h;
      h[0] = xa[2]; h[1] = xa[3];
      *(u32x2*)(sXD[cur] + srow*72 + kap[1]) = h;
      h[0] = xb[0]; h[1] = xb[1];
      *(u32x2*)(sXD[cur] + srow*72 + kap[2]) = h;
      h[0] = xb[2]; h[1] = xb[3];
      *(u32x2*)(sXD[cur] + srow*72 + kap[3]) = h;
    }
    __syncthreads();                    // SINGLE barrier: dbuf covers WAR tail
    if (tj < 15) LOADT(tj + 1);         // T14: issue early, lands next iter
    // y = z^T tiles (operands swapped): lane holds A[i=wrow+l15][j=v*16+lr4*4+e]
    f32x4 y[4];
    #pragma unroll
    for (int v = 0; v < 4; ++v){
      y[v] = MFMA16(ld72(sB1[cur], v*16, 0,  lane), a1[0],  fz);
      y[v] = MFMA16(ld72(sB2[cur], v*16, 0,  lane), na2[0], y[v]);
      y[v] = MFMA16(ld72(sB1[cur], v*16, 32, lane), a1[1],  y[v]);
      y[v] = MFMA16(ld72(sB2[cur], v*16, 32, lane), na2[1], y[v]);
    }
    // A-frags built in registers: pa0 = [q(y0),q(y1)], pa1 = [q(y2),q(y3)]
    float q[4][4];
    #pragma unroll
    for (int v = 0; v < 4; ++v)
      #pragma unroll
      for (int e = 0; e < 4; ++e)
        q[v][e] = relu_tanh(y[v][e]);
    u32x4 w0, w1;
    asm("v_cvt_pk_bf16_f32 %0, %1, %2" : "=v"(w0[0]) : "v"(q[0][0]), "v"(q[0][1]));
    asm("v_cvt_pk_bf16_f32 %0, %1, %2" : "=v"(w0[1]) : "v"(q[0][2]), "v"(q[0][3]));
    asm("v_cvt_pk_bf16_f32 %0, %1, %2" : "=v"(w0[2]) : "v"(q[1][0]), "v"(q[1][1]));
    asm("v_cvt_pk_bf16_f32 %0, %1, %2" : "=v"(w0[3]) : "v"(q[1][2]), "v"(q[1][3]));
    asm("v_cvt_pk_bf16_f32 %0, %1, %2" : "=v"(w1[0]) : "v"(q[2][0]), "v"(q[2][1]));
    asm("v_cvt_pk_bf16_f32 %0, %1, %2" : "=v"(w1[1]) : "v"(q[2][2]), "v"(q[2][3]));
    asm("v_cvt_pk_bf16_f32 %0, %1, %2" : "=v"(w1[2]) : "v"(q[3][0]), "v"(q[3][1]));
    asm("v_cvt_pk_bf16_f32 %0, %1, %2" : "=v"(w1[3]) : "v"(q[3][2]), "v"(q[3][3]));
    const s16x8 pa0 = *(const s16x8*)&w0;
    const s16x8 pa1 = *(const s16x8*)&w1;
    #pragma unroll
    for (int v = 0; v < 4; ++v){
      ad[v] = MFMA16(pa0, ld72(sXD[cur], v*16, 0,  lane), ad[v]);
      ad[v] = MFMA16(pa1, ld72(sXD[cur], v*16, 32, lane), ad[v]);
    }
  }
#undef LOADT
  const int grow0 = i0 + wrow + (lr4 << 2);
  float disv[4];
  #pragma unroll
  for (int e = 0; e < 4; ++e) disv[e] = rsqrtf(dv[grow0 + e]);
  #pragma unroll
  for (int v = 0; v < 4; ++v){
    const int o = v*16 + l15;
    #pragma unroll
    for (int e = 0; e < 4; ++e){
      const float xw = b2f(xd[(size_t)o*NN + grow0 + e]);   // identity: xdv_i
      outT[(tb*NN + grow0 + e)*OO + o] = disv[e]*(ad[v][e] + xw);
    }
  }
}

// ------------ K5: out = transpose(outT + x0w + outSta) -> [B,N,O,T] ------
__global__ __launch_bounds__(256) void k5(const float* __restrict__ outT,
                                          const u16* __restrict__ x0w,
                                          const u16* __restrict__ outSta,
                                          float* __restrict__ out){
  __shared__ float s[16*64*12];
  const int tid = threadIdx.x;
  const int nb = blockIdx.x, b = blockIdx.y;
  const int n0 = nb * 16;
  for (int t = 0; t < TT; ++t){
    for (int k = tid; k < 1024; k += 256){
      const int r = k >> 6, o = k & 63;
      const size_t idx = (((size_t)t*BB + b)*NN + n0 + r)*OO + o;
      s[(r*64 + o)*12 + t] = outT[idx] + b2f(x0w[idx]) + b2f(outSta[idx]);
    }
  }
  __syncthreads();
  float* dst = out + (size_t)(b*NN + n0)*OO*TT;
  for (int k = tid; k < 16*64*12; k += 256) dst[k] = s[k];
}

extern "C" void kernel_launch(void* const* d_in, const int* in_sizes, int n_in,
                              void* d_out, int out_size, void* d_ws, size_t ws_size,
                              hipStream_t stream) {
  const float* x   = (const float*)d_in[0];
  const float* adj = (const float*)d_in[1];
  const float* W0  = (const float*)d_in[2];
  const float* b0  = (const float*)d_in[3];
  const float* Ws  = (const float*)d_in[4];
  const float* bs  = (const float*)d_in[5];
  const float* Wd  = (const float*)d_in[6];
  const float* bd  = (const float*)d_in[7];
  const float* E1  = (const float*)d_in[8];
  const float* E2  = (const float*)d_in[9];
  float* out = (float*)d_out;

  char* w = (char*)d_ws;
  size_t off = 0;
  auto take = [&](size_t bytes) -> char* {
    char* p = w + off;
    off += bytes; off = (off + 255) & ~(size_t)255;
    return p;
  };
  const size_t NE = (size_t)TT*BB*NN*OO;
  u16*   xt    = (u16*)  take(NE*2);
  u16*   adjb  = (u16*)  take((size_t)NN*NN*2);
  u16*   DE1   = (u16*)  take(NE*2);
  u16*   DE2   = (u16*)  take(NE*2);
  float* rowsum= (float*)take((size_t)TT*BB*NN*4);
  u16*   xdvT  = (u16*)  take(NE*2);
  u16*   xswT  = (u16*)  take(NE*2);
  u16*   x0w   = (u16*)  take(NE*2);
  u16*   outSta= (u16*)  take(NE*2);
  float* outT  = (float*)take(NE*4);

  k0_transpose<<<dim3(NN, BB), 256, 0, stream>>>(x, xt);
  kprep<<<dim3((NN*NN)/1024), 256, 0, stream>>>(adj, adjb, rowsum);
  k1_de<<<dim3(16, BB, TT), 256, 0, stream>>>(xt, Wd, bd, E1, E2, DE1, DE2);
  k2a<<<dim3(8*BB*TT), 256, 0, stream>>>(DE1, DE2, rowsum);
  k3b<<<dim3(8, BB, TT), 256, 0, stream>>>(xt, Wd, Ws, W0, bd, bs, b0,
                                           rowsum, xdvT, xswT, x0w);
  k4s<<<dim3(16*BB*TT), 256, 0, stream>>>(adjb, xswT, outSta);
  k2bf<<<dim3(16*BB*TT), 256, 0, stream>>>(DE1, DE2, xdvT, rowsum, outT);
  k5<<<dim3(NN/16, BB), 256, 0, stream>>>(outT, x0w, outSta, out);
}

// Round 22
// 217.126 us; speedup vs baseline: 1.0403x; 1.0403x over previous
//
#include <hip/hip_runtime.h>

#define BB 8
#define NN 1024
#define CC 64
#define TT 12
#define OO 64

typedef unsigned short u16;
typedef __attribute__((ext_vector_type(8))) short s16x8;
typedef __attribute__((ext_vector_type(4))) float f32x4;
typedef __attribute__((ext_vector_type(4))) unsigned int u32x4;
typedef __attribute__((ext_vector_type(2))) unsigned int u32x2;

__device__ __forceinline__ u16 f2bu(float f){
  union { float f; unsigned u; } v; v.f = f;
  unsigned r = v.u + 0x7FFFu + ((v.u >> 16) & 1u);
  return (u16)(r >> 16);
}
__device__ __forceinline__ float b2f(u16 h){
  union { unsigned u; float f; } v; v.u = ((unsigned)h) << 16; return v.f;
}
// q = relu(tanh(d)) = max(1 - 2/(exp(2d)+1), 0)
__device__ __forceinline__ float relu_tanh(float d){
  float e = __expf(2.0f * d);
  return fmaxf(1.0f - 2.0f * __builtin_amdgcn_rcpf(e + 1.0f), 0.0f);
}
// signed tanh via the same 2-transcendental form
__device__ __forceinline__ float tanh_fast(float d){
  float e = __expf(2.0f * d);
  return 1.0f - 2.0f * __builtin_amdgcn_rcpf(e + 1.0f);
}
__device__ __forceinline__ float tanh_sgn(float x){
  float ax = fabsf(x);
  float e = __expf(2.0f * ax);
  float t = 1.0f - 2.0f * __builtin_amdgcn_rcpf(e + 1.0f);
  return x < 0.0f ? -t : t;
}

#define MFMA16(a,b,c) __builtin_amdgcn_mfma_f32_16x16x32_bf16((a),(b),(c),0,0,0)

// frag load from padded-72 row-major LDS tile (row stride 144B = 9x16B, aligned)
__device__ __forceinline__ s16x8 ld72(const u16* s, int row0, int ko, int lane){
  return *(const s16x8*)(s + (row0 + (lane & 15)) * 72 + ko + ((lane >> 4) << 3));
}

// ---------------- K0: x [B,N,C,T] f32 -> xt [T,B,N,C] bf16 ----------------
__global__ __launch_bounds__(256) void k0_transpose(const float* __restrict__ x,
                                                    u16* __restrict__ xt){
  const int n = blockIdx.x, b = blockIdx.y;
  __shared__ float s[CC*TT];
  const float* src = x + (size_t)(b*NN + n)*CC*TT;
  for (int k = threadIdx.x; k < CC*TT; k += 256) s[k] = src[k];
  __syncthreads();
  for (int k = threadIdx.x; k < CC*TT; k += 256){
    const int t = k >> 6, c = k & 63;
    xt[(((size_t)t*BB + b)*NN + n)*CC + c] = f2bu(s[c*TT + t]);
  }
}

// ------ kprep: adj f32 -> bf16 AND rowsum init (merged launches) ------
__global__ __launch_bounds__(256) void kprep(const float* __restrict__ adj,
                                             u16* __restrict__ adjb,
                                             float* __restrict__ rs){
  const size_t i = ((size_t)blockIdx.x*256 + threadIdx.x)*4;
  if (i < (size_t)NN*NN){
    const float4 v = *(const float4*)(adj + i);
    u16 o0=f2bu(v.x), o1=f2bu(v.y), o2=f2bu(v.z), o3=f2bu(v.w);
    adjb[i]=o0; adjb[i+1]=o1; adjb[i+2]=o2; adjb[i+3]=o3;
  }
  const size_t j = (size_t)blockIdx.x*256 + threadIdx.x;
  if (j < (size_t)TT*BB*NN) rs[j] = 1.0f;   // +I contribution to degree
}

// ---- K1: base = xt@Wd + bd; DE1/2 = tanh(base*E1/2), direct stores ----
__global__ __launch_bounds__(256) void k1_de(const u16* __restrict__ xt,
    const float* __restrict__ Wd, const float* __restrict__ bd,
    const float* __restrict__ E1, const float* __restrict__ E2,
    u16* __restrict__ DE1g, u16* __restrict__ DE2g){
  __shared__ __align__(16) u16 sWd[64*72];   // W^T [o][c]
  const int tid = threadIdx.x, lane = tid & 63, wid = tid >> 6;
  const int l15 = lane & 15, lr4 = lane >> 4;
  const int it = blockIdx.x, b = blockIdx.y, t = blockIdx.z;
  const int n0 = it * 64;
  for (int k = tid; k < 4096; k += 256){
    const int o = k & 63, c = k >> 6;
    sWd[o*72 + c] = f2bu(Wd[(size_t)t*4096 + c*64 + o]);
  }
  __syncthreads();
  const size_t tb = (size_t)t*BB + b;
  const u16* gx = xt + (tb*NN + n0)*CC;
  const int wrow = wid * 16;
  const f32x4 fz = {0.f,0.f,0.f,0.f};
  f32x4 acc[4] = {fz, fz, fz, fz};
  #pragma unroll
  for (int ks = 0; ks < 2; ++ks){
    const int ko = ks*32;
    const s16x8 a = *(const s16x8*)(gx + (wrow + l15)*CC + ko + (lr4 << 3));
    #pragma unroll
    for (int v = 0; v < 4; ++v)
      acc[v] = MFMA16(a, ld72(sWd, v*16, ko, lane), acc[v]);
  }
  #pragma unroll
  for (int v = 0; v < 4; ++v){
    const int o = v*16 + l15;
    const float bdv = bd[t*OO + o];
    #pragma unroll
    for (int e = 0; e < 4; ++e){
      const int n = n0 + wrow + (lr4 << 2) + e;
      const float base = acc[v][e] + bdv;
      const size_t eo = ((size_t)t*NN + n)*OO + o;
      const size_t so = (tb*NN + n)*OO + o;
      DE1g[so] = f2bu(tanh_sgn(base * E1[eo]));
      DE2g[so] = f2bu(tanh_sgn(base * E2[eo]));
    }
  }
}

// ---- K2a: PASS 1 — rowsum via UPPER-TRIANGLE only. Strip pair (p, 15-p),
//      j-tiles DOUBLE-BUFFERED in the dead i-side buffers: 1 barrier/iter. ----
__global__ __launch_bounds__(256) void k2a(const u16* __restrict__ DE1g,
    const u16* __restrict__ DE2g, float* __restrict__ rowsum){
  __shared__ __align__(16) u16 sb0[64*72], sb1[64*72];     // buf pair 0
  __shared__ __align__(16) u16 sb2[64*72], sb3[64*72];     // buf pair 1
  const int tid = threadIdx.x, lane = tid & 63, wid = tid >> 6;
  const int l15 = lane & 15, lr4 = lane >> 4;
  const int nwg = 8*BB*TT;                                 // 768
  const int logical = ((int)blockIdx.x & 7)*(nwg >> 3) + ((int)blockIdx.x >> 3);
  const int p = logical & 7;
  const size_t tb = (size_t)(logical >> 3);                // t*BB + b
  const int tiA = p, tiB = 15 - p;
  const u16* g1 = DE1g + tb*NN*OO;
  const u16* g2 = DE2g + tb*NN*OO;
  for (int k = tid; k < 512; k += 256){
    const int r = k >> 3, c = (k & 7) << 3;
    *(s16x8*)(sb0 + r*72 + c) = *(const s16x8*)(g1 + (size_t)(tiA*64 + r)*OO + c);
    s16x8 vA = *(const s16x8*)(g2 + (size_t)(tiA*64 + r)*OO + c);
    u32x4 wA = *(u32x4*)&vA; wA ^= 0x80008000u;            // negate 8 bf16
    *(u32x4*)(sb1 + r*72 + c) = wA;
    *(s16x8*)(sb2 + r*72 + c) = *(const s16x8*)(g1 + (size_t)(tiB*64 + r)*OO + c);
    s16x8 vB = *(const s16x8*)(g2 + (size_t)(tiB*64 + r)*OO + c);
    u32x4 wB = *(u32x4*)&vB; wB ^= 0x80008000u;
    *(u32x4*)(sb3 + r*72 + c) = wB;
  }
  __syncthreads();
  const int wrow = wid * 16;
  s16x8 a1A[2], na2A[2], a1B[2], na2B[2];
  #pragma unroll
  for (int ks = 0; ks < 2; ++ks){
    a1A[ks]  = ld72(sb0, wrow, ks*32, lane);
    na2A[ks] = ld72(sb1, wrow, ks*32, lane);
    a1B[ks]  = ld72(sb2, wrow, ks*32, lane);
    na2B[ks] = ld72(sb3, wrow, ks*32, lane);
  }
  const int srow = tid >> 2, sc0 = (tid & 3) << 4;
  s16x8 pB1a,pB1b, pB2a,pB2b;
#define LOADT(TJ) do { \
    pB1a = *(const s16x8*)(g2 + (size_t)((TJ)*64 + srow)*OO + sc0); \
    pB1b = *(const s16x8*)(g2 + (size_t)((TJ)*64 + srow)*OO + sc0 + 8); \
    pB2a = *(const s16x8*)(g1 + (size_t)((TJ)*64 + srow)*OO + sc0); \
    pB2b = *(const s16x8*)(g1 + (size_t)((TJ)*64 + srow)*OO + sc0 + 8); \
  } while (0)
  LOADT(p);
  float rpA[4] = {0.f,0.f,0.f,0.f}, rpB[4] = {0.f,0.f,0.f,0.f};
  const f32x4 fz = {0.f,0.f,0.f,0.f};
  float* rsg = rowsum + tb*NN;
  __syncthreads();                      // all waves hold a-frags before overwrite
  for (int tj = p; tj < 16; ++tj){
    u16* sJ1 = ((tj - p) & 1) ? sb2 : sb0;
    u16* sJ2 = ((tj - p) & 1) ? sb3 : sb1;
    *(s16x8*)(sJ1 + srow*72 + sc0)     = pB1a;
    *(s16x8*)(sJ1 + srow*72 + sc0 + 8) = pB1b;
    *(s16x8*)(sJ2 + srow*72 + sc0)     = pB2a;
    *(s16x8*)(sJ2 + srow*72 + sc0 + 8) = pB2b;
    __syncthreads();                    // single barrier: dbuf covers the tail
    if (tj < 15) LOADT(tj + 1);         // T14: issue early, lands next iter
    s16x8 b1[4], b2[4], b1h[4], b2h[4];
    #pragma unroll
    for (int v = 0; v < 4; ++v){
      b1[v]  = ld72(sJ1, v*16, 0,  lane);
      b2[v]  = ld72(sJ2, v*16, 0,  lane);
      b1h[v] = ld72(sJ1, v*16, 32, lane);
      b2h[v] = ld72(sJ2, v*16, 32, lane);
    }
    {   // strip A
      f32x4 z[4];
      #pragma unroll
      for (int v = 0; v < 4; ++v){
        z[v] = MFMA16(a1A[0],  b1[v],  fz);
        z[v] = MFMA16(na2A[0], b2[v],  z[v]);
        z[v] = MFMA16(a1A[1],  b1h[v], z[v]);
        z[v] = MFMA16(na2A[1], b2h[v], z[v]);
      }
      float colp[4] = {0.f,0.f,0.f,0.f};
      #pragma unroll
      for (int v = 0; v < 4; ++v)
        #pragma unroll
        for (int e = 0; e < 4; ++e){
          const float th = tanh_fast(z[v][e]);
          rpA[e]  += fmaxf(th, 0.f);
          colp[v] += fmaxf(-th, 0.f);
        }
      if (tj > tiA){
        #pragma unroll
        for (int v = 0; v < 4; ++v){
          float c = colp[v];
          c += __shfl_xor(c, 16); c += __shfl_xor(c, 32);
          if (lane < 16) atomicAdd(&rsg[tj*64 + v*16 + lane], c);
        }
      }
    }
    if (tj >= tiB){   // strip B
      f32x4 z[4];
      #pragma unroll
      for (int v = 0; v < 4; ++v){
        z[v] = MFMA16(a1B[0],  b1[v],  fz);
        z[v] = MFMA16(na2B[0], b2[v],  z[v]);
        z[v] = MFMA16(a1B[1],  b1h[v], z[v]);
        z[v] = MFMA16(na2B[1], b2h[v], z[v]);
      }
      float colp[4] = {0.f,0.f,0.f,0.f};
      #pragma unroll
      for (int v = 0; v < 4; ++v)
        #pragma unroll
        for (int e = 0; e < 4; ++e){
          const float th = tanh_fast(z[v][e]);
          rpB[e]  += fmaxf(th, 0.f);
          colp[v] += fmaxf(-th, 0.f);
        }
      if (tj > tiB){
        #pragma unroll
        for (int v = 0; v < 4; ++v){
          float c = colp[v];
          c += __shfl_xor(c, 16); c += __shfl_xor(c, 32);
          if (lane < 16) atomicAdd(&rsg[tj*64 + v*16 + lane], c);
        }
      }
    }
  }
#undef LOADT
  #pragma unroll
  for (int e = 0; e < 4; ++e){
    float r = rpA[e];
    r += __shfl_xor(r, 1); r += __shfl_xor(r, 2);
    r += __shfl_xor(r, 4); r += __shfl_xor(r, 8);
    if (l15 == 0) atomicAdd(&rsg[tiA*64 + wrow + (lr4 << 2) + e], r);
  }
  #pragma unroll
  for (int e = 0; e < 4; ++e){
    float r = rpB[e];
    r += __shfl_xor(r, 1); r += __shfl_xor(r, 2);
    r += __shfl_xor(r, 4); r += __shfl_xor(r, 8);
    if (l15 == 0) atomicAdd(&rsg[tiB*64 + wrow + (lr4 << 2) + e], r);
  }
}

// ---- K3b (after k2a): xdv' = rsqrt(rowsum)*0.475*x@Wd ; xsw' = 0.475*x@Ws
//      ([o][n]); x0w = 0.05*x@W0 + all biases ([n][o]) ----
__global__ __launch_bounds__(256) void k3b(const u16* __restrict__ xt,
    const float* __restrict__ Wd, const float* __restrict__ Ws,
    const float* __restrict__ W0, const float* __restrict__ bd,
    const float* __restrict__ bs, const float* __restrict__ b0,
    const float* __restrict__ rowsum, u16* __restrict__ xdvT,
    u16* __restrict__ xswT, u16* __restrict__ x0w){
  __shared__ __align__(16) u16 sW[64*72];
  const int tid = threadIdx.x, lane = tid & 63, wid = tid >> 6;
  const int l15 = lane & 15, lr4 = lane >> 4;
  const int it = blockIdx.x, b = blockIdx.y, t = blockIdx.z;
  const size_t tb = (size_t)t*BB + b;
  const int n0 = it * 128, wrow = wid * 32;
  const float* dvb = rowsum + tb*NN + n0;
  float dis[2][4];
  #pragma unroll
  for (int u = 0; u < 2; ++u)
    #pragma unroll
    for (int e = 0; e < 4; ++e)
      dis[u][e] = rsqrtf(dvb[wrow + u*16 + (lr4 << 2) + e]);
  float badd[4];
  #pragma unroll
  for (int v = 0; v < 4; ++v){
    const int o = v*16 + l15;
    badd[v] = 0.475f*(bd[t*OO + o] + bs[t*OO + o]) + 0.05f*b0[o];
  }
  const u16* gx = xt + (tb*NN + n0)*CC;
  const f32x4 fz = {0.f,0.f,0.f,0.f};
  for (int pass = 0; pass < 3; ++pass){
    __syncthreads();
    {
      const float* Wsrc = (pass == 0) ? (Wd + (size_t)t*4096)
                        : (pass == 1) ? (Ws + (size_t)t*4096) : W0;
      const float scale = (pass == 2) ? 0.05f : 0.475f;
      for (int k = tid; k < 4096; k += 256){
        const int o = k & 63, c = k >> 6;
        sW[o*72 + c] = f2bu(scale * Wsrc[c*64 + o]);
      }
    }
    __syncthreads();
    f32x4 acc[2][4];
    #pragma unroll
    for (int u = 0; u < 2; ++u)
      #pragma unroll
      for (int v = 0; v < 4; ++v) acc[u][v] = fz;
    #pragma unroll
    for (int ks = 0; ks < 2; ++ks){
      const int ko = ks*32;
      s16x8 bw[4];
      #pragma unroll
      for (int v = 0; v < 4; ++v) bw[v] = ld72(sW, v*16, ko, lane);
      #pragma unroll
      for (int u = 0; u < 2; ++u){
        const s16x8 a = *(const s16x8*)(gx + (wrow + u*16 + l15)*CC + ko + (lr4 << 3));
        #pragma unroll
        for (int v = 0; v < 4; ++v) acc[u][v] = MFMA16(a, bw[v], acc[u][v]);
      }
    }
    #pragma unroll
    for (int u = 0; u < 2; ++u)
      #pragma unroll
      for (int v = 0; v < 4; ++v){
        const int o = v*16 + l15;
        #pragma unroll
        for (int e = 0; e < 4; ++e){
          const int nl = wrow + u*16 + (lr4 << 2) + e;
          float val = acc[u][v][e];
          if (pass == 0)      xdvT[(tb*OO + o)*NN + n0 + nl] = f2bu(val * dis[u][e]);
          else if (pass == 1) xswT[(tb*OO + o)*NN + n0 + nl] = f2bu(val);
          else                x0w[(tb*NN + n0 + nl)*OO + o]  = f2bu(val + badd[v]);
        }
      }
  }
}

// ---- K4s: outSta = adj@xsw'  (bf16, [n][o]) — ti-major XCD swizzle. ----
__global__ __launch_bounds__(256) void k4s(const u16* __restrict__ adjb,
    const u16* __restrict__ xswT, u16* __restrict__ outSta){
  __shared__ __align__(16) u16 sJ[64*72], sS[64*72];   // 18.4KB
  const int tid = threadIdx.x, lane = tid & 63, wid = tid >> 6;
  const int l15 = lane & 15, lr4 = lane >> 4;
  const int nwg = 16*BB*TT;                            // 1536
  const int logical = ((int)blockIdx.x & 7)*(nwg >> 3) + ((int)blockIdx.x >> 3);
  const int ti = logical / (BB*TT);                    // ti-major: adj reuse
  const size_t tb = (size_t)(logical % (BB*TT));
  const u16* xs = xswT + tb*OO*NN;
  const int i0 = ti * 64, wrow = wid * 16;
  const int srow = tid >> 2, sc0 = (tid & 3) << 4;
  s16x8 pJa, pJb, pSa, pSb;
#define LOADS(TJ) do { \
    pJa = *(const s16x8*)(adjb + (size_t)(i0 + srow)*NN + (TJ)*64 + sc0); \
    pJb = *(const s16x8*)(adjb + (size_t)(i0 + srow)*NN + (TJ)*64 + sc0 + 8); \
    pSa = *(const s16x8*)(xs   + (size_t)srow*NN + (TJ)*64 + sc0); \
    pSb = *(const s16x8*)(xs   + (size_t)srow*NN + (TJ)*64 + sc0 + 8); \
  } while (0)
  LOADS(0);
  const f32x4 fz = {0.f,0.f,0.f,0.f};
  f32x4 as_[4] = {fz,fz,fz,fz};
  for (int tj = 0; tj < 16; ++tj){
    *(s16x8*)(sJ + srow*72 + sc0)     = pJa;
    *(s16x8*)(sJ + srow*72 + sc0 + 8) = pJb;
    *(s16x8*)(sS + srow*72 + sc0)     = pSa;
    *(s16x8*)(sS + srow*72 + sc0 + 8) = pSb;
    __syncthreads();
    if (tj < 15) LOADS(tj + 1);        // T14: lands during compute
    const s16x8 aJ0 = ld72(sJ, wrow, 0,  lane);
    const s16x8 aJ1 = ld72(sJ, wrow, 32, lane);
    #pragma unroll
    for (int v = 0; v < 4; ++v){
      as_[v] = MFMA16(aJ0, ld72(sS, v*16, 0,  lane), as_[v]);
      as_[v] = MFMA16(aJ1, ld72(sS, v*16, 32, lane), as_[v]);
    }
    __syncthreads();                   // frag reads done before next ds_write
  }
#undef LOADS
  #pragma unroll
  for (int v = 0; v < 4; ++v){
    const int o = v*16 + l15;
    #pragma unroll
    for (int e = 0; e < 4; ++e){
      const int n = i0 + wrow + (lr4 << 2) + e;
      outSta[(tb*NN + n)*OO + o] = f2bu(as_[v][e]);
    }
  }
}

// ---- K2bf: PASS 2 — swapped MFMA (y = z^T); A-frags built IN REGISTERS
//      (cvt_pk), PV consumes directly; xdv staged k-PERMUTED (sigma). ----
__global__ __launch_bounds__(256) void k2bf(const u16* __restrict__ DE1g,
    const u16* __restrict__ DE2g, const u16* __restrict__ xdvT,
    const float* __restrict__ rowsum, float* __restrict__ outT){
  __shared__ __align__(16) u16 sB1[64*72], sB2[64*72], sXD[64*72];  // 27.6KB
  const int tid = threadIdx.x, lane = tid & 63, wid = tid >> 6;
  const int l15 = lane & 15, lr4 = lane >> 4;
  const int nwg = 16*BB*TT;                                // 1536
  const int logical = ((int)blockIdx.x & 7)*(nwg >> 3) + ((int)blockIdx.x >> 3);
  const int ti = logical & 15;
  const size_t tb = (size_t)(logical >> 4);                // t*BB + b
  const u16* g1 = DE1g + tb*NN*OO;
  const u16* g2 = DE2g + tb*NN*OO;
  const u16* xd = xdvT + tb*OO*NN;
  const float* dv = rowsum + tb*NN;
  const int i0 = ti * 64;
  // stage i-side into sB1/sB2 (dead after a-frag extraction; reused in loop)
  for (int k = tid; k < 512; k += 256){
    const int r = k >> 3, c = (k & 7) << 3;
    *(s16x8*)(sB1 + r*72 + c) = *(const s16x8*)(g1 + (size_t)(i0 + r)*OO + c);
    s16x8 v = *(const s16x8*)(g2 + (size_t)(i0 + r)*OO + c);
    u32x4 w = *(u32x4*)&v; w ^= 0x80008000u;
    *(u32x4*)(sB2 + r*72 + c) = w;
  }
  __syncthreads();
  const int wrow = wid * 16;
  s16x8 a1[2], na2[2];
  #pragma unroll
  for (int ks = 0; ks < 2; ++ks){
    a1[ks]  = ld72(sB1, wrow, ks*32, lane);
    na2[ks] = ld72(sB2, wrow, ks*32, lane);
  }
  const int srow = tid >> 2, sc0 = (tid & 3) << 4;
  // sigma^-1 k-positions for the 4 j-groups this thread stages (8B each):
  // g = sc0/4 + q;  kappa = (g&3)*8 + ((g>>2)&1)*4 + (g>>3)*32
  const int g0 = sc0 >> 2;
  int kap[4];
  #pragma unroll
  for (int q = 0; q < 4; ++q){
    const int g = g0 + q;
    kap[q] = ((g & 3) << 3) + (((g >> 2) & 1) << 2) + ((g >> 3) << 5);
  }
  s16x8 pB1a,pB1b, pB2a,pB2b, pXDa,pXDb;
#define LOADT(TJ) do { \
    pB1a = *(const s16x8*)(g2 + (size_t)((TJ)*64 + srow)*OO + sc0); \
    pB1b = *(const s16x8*)(g2 + (size_t)((TJ)*64 + srow)*OO + sc0 + 8); \
    pB2a = *(const s16x8*)(g1 + (size_t)((TJ)*64 + srow)*OO + sc0); \
    pB2b = *(const s16x8*)(g1 + (size_t)((TJ)*64 + srow)*OO + sc0 + 8); \
    pXDa = *(const s16x8*)(xd + (size_t)srow*NN + (TJ)*64 + sc0); \
    pXDb = *(const s16x8*)(xd + (size_t)srow*NN + (TJ)*64 + sc0 + 8); \
  } while (0)
  LOADT(0);
  const f32x4 fz = {0.f,0.f,0.f,0.f};
  f32x4 ad[4] = {fz,fz,fz,fz};
  __syncthreads();                      // all waves read a-frags before overwrite
  for (int tj = 0; tj < 16; ++tj){
    *(s16x8*)(sB1 + srow*72 + sc0)     = pB1a;
    *(s16x8*)(sB1 + srow*72 + sc0 + 8) = pB1b;
    *(s16x8*)(sB2 + srow*72 + sc0)     = pB2a;
    *(s16x8*)(sB2 + srow*72 + sc0 + 8) = pB2b;
    {   // xdv staged into sigma-permuted k-columns (4x b64)
      const u32x4 xa = *(const u32x4*)&pXDa;
      const u32x4 xb = *(const u32x4*)&pXDb;
      u32x2 h;
      h[0] = xa[0]; h[1] = xa[1];
      *(u32x2*)(sXD + srow*72 + kap[0]) = h;
      h[0] = xa[2]; h[1] = xa[3];
      *(u32x2*)(sXD + srow*72 + kap[1]) = h;
      h[0] = xb[0]; h[1] = xb[1];
      *(u32x2*)(sXD + srow*72 + kap[2]) = h;
      h[0] = xb[2]; h[1] = xb[3];
      *(u32x2*)(sXD + srow*72 + kap[3]) = h;
    }
    __syncthreads();
    if (tj < 15) LOADT(tj + 1);         // T14: issue early, lands next iter
    // y = z^T tiles (operands swapped): lane holds A[i=wrow+l15][j=v*16+lr4*4+e]
    f32x4 y[4];
    #pragma unroll
    for (int v = 0; v < 4; ++v){
      y[v] = MFMA16(ld72(sB1, v*16, 0,  lane), a1[0],  fz);
      y[v] = MFMA16(ld72(sB2, v*16, 0,  lane), na2[0], y[v]);
      y[v] = MFMA16(ld72(sB1, v*16, 32, lane), a1[1],  y[v]);
      y[v] = MFMA16(ld72(sB2, v*16, 32, lane), na2[1], y[v]);
    }
    // A-frags built in registers: pa0 = [q(y0),q(y1)], pa1 = [q(y2),q(y3)]
    float q[4][4];
    #pragma unroll
    for (int v = 0; v < 4; ++v)
      #pragma unroll
      for (int e = 0; e < 4; ++e)
        q[v][e] = relu_tanh(y[v][e]);
    u32x4 w0, w1;
    asm("v_cvt_pk_bf16_f32 %0, %1, %2" : "=v"(w0[0]) : "v"(q[0][0]), "v"(q[0][1]));
    asm("v_cvt_pk_bf16_f32 %0, %1, %2" : "=v"(w0[1]) : "v"(q[0][2]), "v"(q[0][3]));
    asm("v_cvt_pk_bf16_f32 %0, %1, %2" : "=v"(w0[2]) : "v"(q[1][0]), "v"(q[1][1]));
    asm("v_cvt_pk_bf16_f32 %0, %1, %2" : "=v"(w0[3]) : "v"(q[1][2]), "v"(q[1][3]));
    asm("v_cvt_pk_bf16_f32 %0, %1, %2" : "=v"(w1[0]) : "v"(q[2][0]), "v"(q[2][1]));
    asm("v_cvt_pk_bf16_f32 %0, %1, %2" : "=v"(w1[1]) : "v"(q[2][2]), "v"(q[2][3]));
    asm("v_cvt_pk_bf16_f32 %0, %1, %2" : "=v"(w1[2]) : "v"(q[3][0]), "v"(q[3][1]));
    asm("v_cvt_pk_bf16_f32 %0, %1, %2" : "=v"(w1[3]) : "v"(q[3][2]), "v"(q[3][3]));
    const s16x8 pa0 = *(const s16x8*)&w0;
    const s16x8 pa1 = *(const s16x8*)&w1;
    #pragma unroll
    for (int v = 0; v < 4; ++v){
      ad[v] = MFMA16(pa0, ld72(sXD, v*16, 0,  lane), ad[v]);
      ad[v] = MFMA16(pa1, ld72(sXD, v*16, 32, lane), ad[v]);
    }
    __syncthreads();                    // frag reads done before next ds_write
  }
#undef LOADT
  const int grow0 = i0 + wrow + (lr4 << 2);
  float disv[4];
  #pragma unroll
  for (int e = 0; e < 4; ++e) disv[e] = rsqrtf(dv[grow0 + e]);
  #pragma unroll
  for (int v = 0; v < 4; ++v){
    const int o = v*16 + l15;
    #pragma unroll
    for (int e = 0; e < 4; ++e){
      const float xw = b2f(xd[(size_t)o*NN + grow0 + e]);   // identity: xdv_i
      outT[(tb*NN + grow0 + e)*OO + o] = disv[e]*(ad[v][e] + xw);
    }
  }
}

// ------------ K5: out = transpose(outT + x0w + outSta) -> [B,N,O,T] ------
__global__ __launch_bounds__(256) void k5(const float* __restrict__ outT,
                                          const u16* __restrict__ x0w,
                                          const u16* __restrict__ outSta,
                                          float* __restrict__ out){
  __shared__ float s[16*64*12];
  const int tid = threadIdx.x;
  const int nb = blockIdx.x, b = blockIdx.y;
  const int n0 = nb * 16;
  for (int t = 0; t < TT; ++t){
    for (int k = tid; k < 1024; k += 256){
      const int r = k >> 6, o = k & 63;
      const size_t idx = (((size_t)t*BB + b)*NN + n0 + r)*OO + o;
      s[(r*64 + o)*12 + t] = outT[idx] + b2f(x0w[idx]) + b2f(outSta[idx]);
    }
  }
  __syncthreads();
  float* dst = out + (size_t)(b*NN + n0)*OO*TT;
  for (int k = tid; k < 16*64*12; k += 256) dst[k] = s[k];
}

extern "C" void kernel_launch(void* const* d_in, const int* in_sizes, int n_in,
                              void* d_out, int out_size, void* d_ws, size_t ws_size,
                              hipStream_t stream) {
  const float* x   = (const float*)d_in[0];
  const float* adj = (const float*)d_in[1];
  const float* W0  = (const float*)d_in[2];
  const float* b0  = (const float*)d_in[3];
  const float* Ws  = (const float*)d_in[4];
  const float* bs  = (const float*)d_in[5];
  const float* Wd  = (const float*)d_in[6];
  const float* bd  = (const float*)d_in[7];
  const float* E1  = (const float*)d_in[8];
  const float* E2  = (const float*)d_in[9];
  float* out = (float*)d_out;

  char* w = (char*)d_ws;
  size_t off = 0;
  auto take = [&](size_t bytes) -> char* {
    char* p = w + off;
    off += bytes; off = (off + 255) & ~(size_t)255;
    return p;
  };
  const size_t NE = (size_t)TT*BB*NN*OO;
  u16*   xt    = (u16*)  take(NE*2);
  u16*   adjb  = (u16*)  take((size_t)NN*NN*2);
  u16*   DE1   = (u16*)  take(NE*2);
  u16*   DE2   = (u16*)  take(NE*2);
  float* rowsum= (float*)take((size_t)TT*BB*NN*4);
  u16*   xdvT  = (u16*)  take(NE*2);
  u16*   xswT  = (u16*)  take(NE*2);
  u16*   x0w   = (u16*)  take(NE*2);
  u16*   outSta= (u16*)  take(NE*2);
  float* outT  = (float*)take(NE*4);

  k0_transpose<<<dim3(NN, BB), 256, 0, stream>>>(x, xt);
  kprep<<<dim3((NN*NN)/1024), 256, 0, stream>>>(adj, adjb, rowsum);
  k1_de<<<dim3(16, BB, TT), 256, 0, stream>>>(xt, Wd, bd, E1, E2, DE1, DE2);
  k2a<<<dim3(8*BB*TT), 256, 0, stream>>>(DE1, DE2, rowsum);
  k3b<<<dim3(8, BB, TT), 256, 0, stream>>>(xt, Wd, Ws, W0, bd, bs, b0,
                                           rowsum, xdvT, xswT, x0w);
  k4s<<<dim3(16*BB*TT), 256, 0, stream>>>(adjb, xswT, outSta);
  k2bf<<<dim3(16*BB*TT), 256, 0, stream>>>(DE1, DE2, xdvT, rowsum, outT);
  k5<<<dim3(NN/16, BB), 256, 0, stream>>>(outT, x0w, outSta, out);
}